// Round 2
// baseline (558.000 us; speedup 1.0000x reference)
//
#include <hip/hip_runtime.h>

// Problem: B=65536 rows, DIM=256, K=1024 codewords.
// out layout (fp32): [0,16777216) quantize | [16777216] diff | [16777217,+65536) indices
#define NROWSQ   65536
#define NDIM     256
#define NCB      1024
#define DIFF_OFF 16777216
#define IDX_OFF  16777217

// bf16 phase-1 decision margin (score units; bf16 dot noise sigma ~0.035)
#define MARGIN_A 0.30f
// fp32 phase-2 decision margin (score units; fp32 noise ~3e-5) -> below this,
// decide with the reference-mimicking fp32 formula.
#define MARGIN_B 1.5e-3f

typedef __attribute__((ext_vector_type(8))) short s16x8;
typedef __attribute__((ext_vector_type(4))) float f32x4;

__device__ __forceinline__ unsigned short f2bf(float f) {
  union { float f; unsigned u; } v; v.f = f;
  return (unsigned short)((v.u + 0x7FFFu + ((v.u >> 16) & 1u)) >> 16);  // RNE
}

__device__ __forceinline__ void top2_update(float& v1, int& i1, float& v2, int& i2,
                                            float v, int col) {
  if (v > v1 || (v == v1 && col < i1)) { v2 = v1; i2 = i1; v1 = v; i1 = col; }
  else if (v > v2 || (v == v2 && col < i2)) { v2 = v; i2 = col; }
}

__device__ __forceinline__ void top2_merge(float& v1, int& i1, float& v2, int& i2,
                                           float ov1, int oi1, float ov2, int oi2) {
  if (ov1 > v1 || (ov1 == v1 && oi1 < i1)) {
    float nv2 = v1; int ni2 = i1;
    if (ov2 > nv2 || (ov2 == nv2 && oi2 < ni2)) { nv2 = ov2; ni2 = oi2; }
    v1 = ov1; i1 = oi1; v2 = nv2; i2 = ni2;
  } else if (ov1 > v2 || (ov1 == v2 && oi1 < i2)) {
    v2 = ov1; i2 = oi1;
  }
}

// numpy pairwise_sum emulation for a contiguous 128-block (8 accumulators).
__device__ __forceinline__ float np_pairwise128(const float* p) {
  float r0 = p[0], r1 = p[1], r2 = p[2], r3 = p[3];
  float r4 = p[4], r5 = p[5], r6 = p[6], r7 = p[7];
  for (int i = 8; i < 128; i += 8) {
    r0 += p[i];     r1 += p[i + 1]; r2 += p[i + 2]; r3 += p[i + 3];
    r4 += p[i + 4]; r5 += p[i + 5]; r6 += p[i + 6]; r7 += p[i + 7];
  }
  return ((r0 + r1) + (r2 + r3)) + ((r4 + r5) + (r6 + r7));
}

// ---------------- k0: prep (esq variants, transposed codebooks, counters) ----
// grid 68 x 256. blocks 0..3: e_sq arrays. blocks 4..67: transpose.
__global__ void k0_prep(const float* __restrict__ E, unsigned short* __restrict__ cbT,
                        float* __restrict__ embT, float* __restrict__ esq32,
                        float* __restrict__ esqr, int* __restrict__ cntA,
                        int* __restrict__ cntB) {
  const int b = blockIdx.x, t = threadIdx.x;
  if (b < 4) {
    const int k = b * 256 + t;
    // high-precision half-norm for the score cascade (k1/k2a)
    double s = 0.0;
    for (int d = 0; d < NDIM; ++d) { double v = (double)E[d * NCB + k]; s += v * v; }
    esq32[k] = (float)(0.5 * s);
    // reference-mimic e_sq: numpy sum(embed*embed, axis=0) = sequential-in-d
    // fp32 add of fp32-rounded products (no fma).
    float sr = 0.f;
    for (int d = 0; d < NDIM; ++d) {
      const float v = E[d * NCB + k];
      const float p = v * v;      // fp32 rounded product
      sr = sr + p;                // fp32 sequential add
    }
    esqr[k] = sr;
    if (b == 0 && t == 0) { *cntA = 0; *cntB = 0; }
  } else {
    const int kb = (b - 4) * 16;
    const int d = t;
    #pragma unroll
    for (int kk = 0; kk < 16; ++kk) {
      const int k = kb + kk;
      const float v = E[d * NCB + k];
      embT[k * NDIM + d] = v;       // coalesced write (t = d consecutive)
      cbT[k * NDIM + d] = f2bf(v);
    }
  }
}

// ---------------- k1: bf16 MFMA scores + top-2 + contested list --------------
// grid 512 x 256 (4 waves). Block = 128 rows; wave = 32 rows (2 m-tiles of 16).
// A fragments live in registers (reused across all N-tiles). B tile in LDS.
#define BLD 264   // padded bf16 leading dim

__global__ __launch_bounds__(256, 2) void k1_scores(
    const float* __restrict__ X, const unsigned short* __restrict__ cbT,
    const float* __restrict__ esq, float* __restrict__ outIdx,
    int* __restrict__ cntA, int* __restrict__ listA) {
  __shared__ __align__(16) unsigned short Bs[64 * BLD];
  const int t = threadIdx.x;
  const int lane = t & 63, w = t >> 6;
  const int l15 = lane & 15, quad = lane >> 4;
  const int rowbase = blockIdx.x * 128;

  // Preload A fragments: lane holds A[m=l15][k=quad*8+j] per (m-tile, ks).
  s16x8 afrag[2][8];
  #pragma unroll
  for (int m = 0; m < 2; ++m) {
    const float* xr = X + (size_t)(rowbase + w * 32 + m * 16 + l15) * NDIM;
    #pragma unroll
    for (int ks = 0; ks < 8; ++ks) {
      const float4 xa = *(const float4*)(xr + ks * 32 + quad * 8);
      const float4 xb = *(const float4*)(xr + ks * 32 + quad * 8 + 4);
      s16x8 a;
      a[0] = (short)f2bf(xa.x); a[1] = (short)f2bf(xa.y);
      a[2] = (short)f2bf(xa.z); a[3] = (short)f2bf(xa.w);
      a[4] = (short)f2bf(xb.x); a[5] = (short)f2bf(xb.y);
      a[6] = (short)f2bf(xb.z); a[7] = (short)f2bf(xb.w);
      afrag[m][ks] = a;
    }
  }

  float v1[2][4], v2[2][4]; int i1[2][4], i2[2][4];
  #pragma unroll
  for (int m = 0; m < 2; ++m)
    #pragma unroll
    for (int r = 0; r < 4; ++r) {
      v1[m][r] = -3.4e38f; v2[m][r] = -3.4e38f;
      i1[m][r] = 0x7fffffff; i2[m][r] = 0x7fffffff;
    }

  for (int nt = 0; nt < 16; ++nt) {
    const int kb = nt * 64;
    __syncthreads();
    // stage B tile: 64 cols x 256 d bf16, stored Bs[col][d] (cbT is [k][d])
    #pragma unroll
    for (int i = 0; i < 8; ++i) {
      const int id = i * 256 + t;       // [0,2048) 16B chunks
      const int c = id >> 5, d8 = id & 31;
      *(uint4*)&Bs[c * BLD + d8 * 8] = *(const uint4*)(cbT + (kb + c) * NDIM + d8 * 8);
    }
    __syncthreads();

    f32x4 acc[2][4];
    #pragma unroll
    for (int m = 0; m < 2; ++m)
      #pragma unroll
      for (int s = 0; s < 4; ++s) acc[m][s] = (f32x4){0.f, 0.f, 0.f, 0.f};

    #pragma unroll
    for (int ks = 0; ks < 8; ++ks) {
      #pragma unroll
      for (int s = 0; s < 4; ++s) {
        const s16x8 b = *(const s16x8*)&Bs[(s * 16 + l15) * BLD + ks * 32 + quad * 8];
        acc[0][s] = __builtin_amdgcn_mfma_f32_16x16x32_bf16(afrag[0][ks], b, acc[0][s], 0, 0, 0);
        acc[1][s] = __builtin_amdgcn_mfma_f32_16x16x32_bf16(afrag[1][ks], b, acc[1][s], 0, 0, 0);
      }
    }

    // epilogue: D row=(quad*4+r), col=l15 within sub-tile s
    #pragma unroll
    for (int s = 0; s < 4; ++s) {
      const int col = kb + s * 16 + l15;
      const float eq = esq[col];
      #pragma unroll
      for (int m = 0; m < 2; ++m)
        #pragma unroll
        for (int r = 0; r < 4; ++r)
          top2_update(v1[m][r], i1[m][r], v2[m][r], i2[m][r], acc[m][s][r] - eq, col);
    }
  }

  // merge across the 16 lanes sharing each row group (xor bits 0..3)
  #pragma unroll
  for (int mask = 1; mask <= 8; mask <<= 1) {
    #pragma unroll
    for (int m = 0; m < 2; ++m)
      #pragma unroll
      for (int r = 0; r < 4; ++r) {
        const float ov1 = __shfl_xor(v1[m][r], mask); const int oi1 = __shfl_xor(i1[m][r], mask);
        const float ov2 = __shfl_xor(v2[m][r], mask); const int oi2 = __shfl_xor(i2[m][r], mask);
        top2_merge(v1[m][r], i1[m][r], v2[m][r], i2[m][r], ov1, oi1, ov2, oi2);
      }
  }

  if (l15 == 0) {
    #pragma unroll
    for (int m = 0; m < 2; ++m)
      #pragma unroll
      for (int r = 0; r < 4; ++r) {
        const int grow = rowbase + w * 32 + m * 16 + quad * 4 + r;
        outIdx[grow] = (float)i1[m][r];
        if (v1[m][r] - v2[m][r] < MARGIN_A) {
          const int p = atomicAdd(cntA, 1);
          listA[p] = grow;
        }
      }
  }
}

// ---------------- k2a: fp32 recompute for contested rows ---------------------
// grid 512 x 256. Block iteration = 8 rows; thread owns 4 cols x 8 rows.
__global__ __launch_bounds__(256) void k2a_refine(
    const float* __restrict__ X, const float* __restrict__ E,
    const float* __restrict__ esq, const int* __restrict__ cntA,
    const int* __restrict__ listA, float* __restrict__ outIdx,
    int* __restrict__ cntB, int* __restrict__ listB) {
  __shared__ float Xs[8][NDIM];
  __shared__ float rv1[4][8], rv2[4][8];
  __shared__ int   ri1[4][8], ri2[4][8];
  const int t = threadIdx.x;
  const int lane = t & 63, w = t >> 6;
  const int cnt = *cntA;
  for (int base = blockIdx.x * 8; base < cnt; base += gridDim.x * 8) {
    const int nrows = min(8, cnt - base);
    __syncthreads();
    for (int r = 0; r < 8; ++r) {
      const int rid = listA[base + min(r, nrows - 1)];
      Xs[r][t] = X[(size_t)rid * NDIM + t];
    }
    __syncthreads();

    float acc[8][4];
    #pragma unroll
    for (int r = 0; r < 8; ++r)
      #pragma unroll
      for (int c = 0; c < 4; ++c) acc[r][c] = 0.f;

    const int k0 = t * 4;
    for (int d = 0; d < NDIM; ++d) {
      const float4 e = *(const float4*)(E + d * NCB + k0);
      #pragma unroll
      for (int r = 0; r < 8; ++r) {
        const float x = Xs[r][d];
        acc[r][0] += x * e.x; acc[r][1] += x * e.y;
        acc[r][2] += x * e.z; acc[r][3] += x * e.w;
      }
    }
    const float eq0 = esq[k0], eq1 = esq[k0 + 1], eq2 = esq[k0 + 2], eq3 = esq[k0 + 3];

    #pragma unroll
    for (int r = 0; r < 8; ++r) {
      float bv1 = -3.4e38f, bv2 = -3.4e38f; int bi1 = 0x7fffffff, bi2 = 0x7fffffff;
      top2_update(bv1, bi1, bv2, bi2, acc[r][0] - eq0, k0);
      top2_update(bv1, bi1, bv2, bi2, acc[r][1] - eq1, k0 + 1);
      top2_update(bv1, bi1, bv2, bi2, acc[r][2] - eq2, k0 + 2);
      top2_update(bv1, bi1, bv2, bi2, acc[r][3] - eq3, k0 + 3);
      #pragma unroll
      for (int mask = 1; mask < 64; mask <<= 1) {
        const float ov1 = __shfl_xor(bv1, mask); const int oi1 = __shfl_xor(bi1, mask);
        const float ov2 = __shfl_xor(bv2, mask); const int oi2 = __shfl_xor(bi2, mask);
        top2_merge(bv1, bi1, bv2, bi2, ov1, oi1, ov2, oi2);
      }
      if (lane == 0) { rv1[w][r] = bv1; ri1[w][r] = bi1; rv2[w][r] = bv2; ri2[w][r] = bi2; }
    }
    __syncthreads();
    if (t < nrows) {
      const int r = t;
      float fv1 = rv1[0][r], fv2 = rv2[0][r]; int fi1 = ri1[0][r], fi2 = ri2[0][r];
      for (int ww = 1; ww < 4; ++ww)
        top2_merge(fv1, fi1, fv2, fi2, rv1[ww][r], ri1[ww][r], rv2[ww][r], ri2[ww][r]);
      const int rid = listA[base + r];
      outIdx[rid] = (float)fi1;
      if (fv1 - fv2 < MARGIN_B) { const int p = atomicAdd(cntB, 1); listB[p] = rid; }
    }
    __syncthreads();
  }
}

// ---------------- k2b: reference-mimicking fp32 for near-tied rows -----------
// Emulates the numpy reference bit-for-bit (best effort):
//   dot[k]  = sequential fp32 FMA over d=0..255 (OpenBLAS sgemm accumulation)
//   e_sq[k] = sequential fp32 sum of rounded products (axis-0 reduce)
//   x_sq    = numpy pairwise sum (two 128-blocks, 8 accumulators each)
//   dist[k] = (x_sq - 2*dot[k]) + e_sq[k], argmin with first-index tie-break.
__global__ __launch_bounds__(256) void k2b_mimic(
    const float* __restrict__ X, const float* __restrict__ E,
    const float* __restrict__ esqr, const int* __restrict__ cntB,
    const int* __restrict__ listB, float* __restrict__ outIdx) {
  __shared__ float Xr[NDIM];
  __shared__ float Psq[NDIM];
  __shared__ float rv[256];
  __shared__ int ri[256];
  const int t = threadIdx.x;
  const int cnt = *cntB;
  for (int j = blockIdx.x; j < cnt; j += gridDim.x) {
    const int rid = listB[j];
    __syncthreads();
    {
      const float x = X[(size_t)rid * NDIM + t];
      Xr[t] = x;
      Psq[t] = x * x;     // fp32 rounded square (numpy x*x elementwise)
    }
    __syncthreads();
    // every thread redundantly computes the numpy-pairwise x_sq (cheap)
    const float x_sq = np_pairwise128(Psq) + np_pairwise128(Psq + 128);

    float best = 3.4e38f; int bidx = 0x7fffffff;
    #pragma unroll
    for (int c = 0; c < 4; ++c) {
      const int k = t + c * 256;
      float acc = 0.f;
      for (int d = 0; d < NDIM; ++d)
        acc = fmaf(Xr[d], E[d * NCB + k], acc);   // strict d-order, single chain
      const float dist = (x_sq - 2.0f * acc) + esqr[k];
      if (dist < best || (dist == best && k < bidx)) { best = dist; bidx = k; }
    }
    rv[t] = best; ri[t] = bidx;
    __syncthreads();
    for (int off = 128; off > 0; off >>= 1) {
      if (t < off) {
        if (rv[t + off] < rv[t] || (rv[t + off] == rv[t] && ri[t + off] < ri[t])) {
          rv[t] = rv[t + off]; ri[t] = ri[t + off];
        }
      }
      __syncthreads();
    }
    if (t == 0) outIdx[rid] = (float)ri[0];
  }
}

// ---------------- k4: gather codeword, write quantize, diff partials ---------
// grid 2048 x 256 (4 waves); wave handles rows W, W+8192, ... (8 rows).
__global__ __launch_bounds__(256) void k4_outputs(
    const float* __restrict__ X, const float* __restrict__ embT,
    const float* __restrict__ idxF, float* __restrict__ outQ,
    float* __restrict__ partial) {
  const int t = threadIdx.x;
  const int lane = t & 63, w = t >> 6;
  const int W = blockIdx.x * 4 + w;
  float s = 0.f;
  #pragma unroll
  for (int i = 0; i < 8; ++i) {
    const int r = W + i * 8192;
    const int idx = (int)idxF[r];
    const float4 q = *(const float4*)(embT + idx * NDIM + lane * 4);
    const float4 x = *(const float4*)(X + (size_t)r * NDIM + lane * 4);
    *(float4*)(outQ + (size_t)r * NDIM + lane * 4) = q;
    const float dx = q.x - x.x, dy = q.y - x.y, dz = q.z - x.z, dw = q.w - x.w;
    s += dx * dx + dy * dy + dz * dz + dw * dw;
  }
  #pragma unroll
  for (int mask = 1; mask < 64; mask <<= 1) s += __shfl_xor(s, mask);
  __shared__ float bs[4];
  if (lane == 0) bs[w] = s;
  __syncthreads();
  if (t == 0) partial[blockIdx.x] = (bs[0] + bs[1] + bs[2] + bs[3]) * (1.0f / 16777216.0f);
}

// ---------------- k5: final diff reduction -----------------------------------
__global__ void k5_reduce(const float* __restrict__ partial, float* __restrict__ outDiff) {
  __shared__ float s[256];
  const int t = threadIdx.x;
  float a = 0.f;
  #pragma unroll
  for (int i = 0; i < 8; ++i) a += partial[t + i * 256];
  s[t] = a;
  __syncthreads();
  for (int off = 128; off > 0; off >>= 1) {
    if (t < off) s[t] += s[t + off];
    __syncthreads();
  }
  if (t == 0) *outDiff = s[0];
}

// ---------------- launch -----------------------------------------------------
extern "C" void kernel_launch(void* const* d_in, const int* in_sizes, int n_in,
                              void* d_out, int out_size, void* d_ws, size_t ws_size,
                              hipStream_t stream) {
  const float* X = (const float*)d_in[0];     // [65536, 256]
  const float* E = (const float*)d_in[1];     // [256, 1024]
  float* out = (float*)d_out;

  char* ws = (char*)d_ws;                     // ~2.1 MB used
  unsigned short* cbT = (unsigned short*)(ws + 0x000000);  // bf16 [1024][256] 512KB
  float*  embT  = (float*) (ws + 0x080000);   // fp32 [1024][256] 1MB
  float*  esq32 = (float*) (ws + 0x180000);   // 4KB
  float*  esqr  = (float*) (ws + 0x181000);   // 4KB (ref-mimic e_sq)
  int* cntA  = (int*)(ws + 0x183000);
  int* cntB  = (int*)(ws + 0x183004);
  int* listA = (int*)(ws + 0x183100);         // 256KB
  int* listB = (int*)(ws + 0x1C3100);         // 256KB
  float* partial = (float*)(ws + 0x203100);   // 8KB

  float* outQ    = out;
  float* outDiff = out + DIFF_OFF;
  float* outIdx  = out + IDX_OFF;

  k0_prep<<<dim3(68), dim3(256), 0, stream>>>(E, cbT, embT, esq32, esqr, cntA, cntB);
  k1_scores<<<dim3(512), dim3(256), 0, stream>>>(X, cbT, esq32, outIdx, cntA, listA);
  k2a_refine<<<dim3(512), dim3(256), 0, stream>>>(X, E, esq32, cntA, listA, outIdx, cntB, listB);
  k2b_mimic<<<dim3(64), dim3(256), 0, stream>>>(X, E, esqr, cntB, listB, outIdx);
  k4_outputs<<<dim3(2048), dim3(256), 0, stream>>>(X, embT, outIdx, outQ, partial);
  k5_reduce<<<dim3(1), dim3(256), 0, stream>>>(partial, outDiff);
}

// Round 3
// 401.920 us; speedup vs baseline: 1.3883x; 1.3883x over previous
//
#include <hip/hip_runtime.h>

// Problem: B=65536 rows, DIM=256, K=1024 codewords.
// out layout (fp32): [0,16777216) quantize | [16777216] diff | [16777217,+65536) indices
#define NROWSQ   65536
#define NDIM     256
#define NCB      1024
#define DIFF_OFF 16777216
#define IDX_OFF  16777217

// bf16 phase-1 margin on 10-bit-quantized shifted scores (bf16 noise sigma ~0.045,
// quantization <=0.031): 0.35 ~ 7sigma.
#define MARGIN_A 0.35f
// fp32 phase-2 margin (fp32 noise ~3e-5) -> below this, numpy-mimic decides.
#define MARGIN_B 1.5e-3f
// positivity shift: score+384 in [~105, ~406] for this data; clamped >=1 for safety.
#define SCORE_SHIFT 384.0f

typedef __attribute__((ext_vector_type(8))) short s16x8;
typedef __attribute__((ext_vector_type(4))) float f32x4;

__device__ __forceinline__ unsigned short f2bf(float f) {
  union { float f; unsigned u; } v; v.f = f;
  return (unsigned short)((v.u + 0x7FFFu + ((v.u >> 16) & 1u)) >> 16);  // RNE
}

// float top2 helpers (k2a only)
__device__ __forceinline__ void top2_update(float& v1, int& i1, float& v2, int& i2,
                                            float v, int col) {
  if (v > v1 || (v == v1 && col < i1)) { v2 = v1; i2 = i1; v1 = v; i1 = col; }
  else if (v > v2 || (v == v2 && col < i2)) { v2 = v; i2 = col; }
}
__device__ __forceinline__ void top2_merge(float& v1, int& i1, float& v2, int& i2,
                                           float ov1, int oi1, float ov2, int oi2) {
  if (ov1 > v1 || (ov1 == v1 && oi1 < i1)) {
    float nv2 = v1; int ni2 = i1;
    if (ov2 > nv2 || (ov2 == nv2 && oi2 < ni2)) { nv2 = ov2; ni2 = oi2; }
    v1 = ov1; i1 = oi1; v2 = nv2; i2 = ni2;
  } else if (ov1 > v2 || (ov1 == v2 && oi1 < i2)) {
    v2 = ov1; i2 = oi1;
  }
}

// numpy pairwise_sum emulation for a contiguous 128-block (8 accumulators).
__device__ __forceinline__ float np_pairwise128(const float* p) {
  float r0 = p[0], r1 = p[1], r2 = p[2], r3 = p[3];
  float r4 = p[4], r5 = p[5], r6 = p[6], r7 = p[7];
  for (int i = 8; i < 128; i += 8) {
    r0 += p[i];     r1 += p[i + 1]; r2 += p[i + 2]; r3 += p[i + 3];
    r4 += p[i + 4]; r5 += p[i + 5]; r6 += p[i + 6]; r7 += p[i + 7];
  }
  return ((r0 + r1) + (r2 + r3)) + ((r4 + r5) + (r6 + r7));
}

// ---------------- k0a: coalesced tiled transpose E[256][1024] -> embT/cbT ----
// grid 64 x 256. block (bk=bid%16, bd=bid/16): 64x64 tile.
__global__ void k0a_transpose(const float* __restrict__ E, float* __restrict__ embT,
                              unsigned short* __restrict__ cbT,
                              int* __restrict__ cntA, int* __restrict__ cntB) {
  __shared__ float T[64][65];
  const int t = threadIdx.x;
  const int kbase = (blockIdx.x & 15) * 64;
  const int dbase = (blockIdx.x >> 4) * 64;
  if (blockIdx.x == 0 && t == 0) { *cntA = 0; *cntB = 0; }
  // load: 64 d-rows x 64 k, coalesced along k
  #pragma unroll
  for (int i = 0; i < 4; ++i) {
    const int cid = i * 256 + t;            // [0,1024) float4 chunks
    const int dl = cid >> 4, kc = cid & 15;
    const float4 v = *(const float4*)(E + (size_t)(dbase + dl) * NCB + kbase + kc * 4);
    T[dl][kc * 4 + 0] = v.x; T[dl][kc * 4 + 1] = v.y;
    T[dl][kc * 4 + 2] = v.z; T[dl][kc * 4 + 3] = v.w;
  }
  __syncthreads();
  // store: 64 k-rows x 64 d, coalesced along d
  #pragma unroll
  for (int i = 0; i < 4; ++i) {
    const int cid = i * 256 + t;
    const int kl = cid >> 4, dc = cid & 15;
    float4 v;
    v.x = T[dc * 4 + 0][kl]; v.y = T[dc * 4 + 1][kl];
    v.z = T[dc * 4 + 2][kl]; v.w = T[dc * 4 + 3][kl];
    *(float4*)(embT + (size_t)(kbase + kl) * NDIM + dbase + dc * 4) = v;
    ushort4 b;
    b.x = f2bf(v.x); b.y = f2bf(v.y); b.z = f2bf(v.z); b.w = f2bf(v.w);
    *(ushort4*)(cbT + (size_t)(kbase + kl) * NDIM + dbase + dc * 4) = b;
  }
}

// ---------------- k0b: esq variants from embT (coalesced rows) ---------------
// grid 132 x 256. blocks 0..127: esq32 (double) + shifted esqs. 128..131: esqr.
__global__ void k0b_esq(const float* __restrict__ embT, float* __restrict__ esq32,
                        float* __restrict__ esqs, float* __restrict__ esqr) {
  const int b = blockIdx.x, t = threadIdx.x;
  if (b < 128) {
    const int col = b * 8 + (t >> 5);
    const int l = t & 31;
    double s = 0.0;
    #pragma unroll
    for (int i = 0; i < 8; ++i) {
      const double v = (double)embT[(size_t)col * NDIM + l + i * 32];
      s += v * v;
    }
    #pragma unroll
    for (int m = 16; m >= 1; m >>= 1) s += __shfl_xor(s, m);
    if (l == 0) {
      esq32[col] = (float)(0.5 * s);
      esqs[col] = (float)(0.5 * s) - SCORE_SHIFT;   // score = dot - esqs (positive)
    }
  } else {
    const int col = (b - 128) * 256 + t;
    float sr = 0.f;
    for (int d = 0; d < NDIM; ++d) {
      const float v = embT[(size_t)col * NDIM + d];
      sr = sr + v * v;        // numpy axis-0 reduce: sequential fp32
    }
    esqr[col] = sr;
  }
}

// ---------------- k1: bf16 MFMA scores + packed-key top-2 + contested list ---
// grid 512 x 256 (4 waves). Block = 128 rows; wave = 32 rows (2 m-tiles of 16).
// A fragments in registers (reused across all 16 N-tiles). B tile in LDS.
// Packed key: (orderable_score_bits & ~1023) | (1023-col)  -> branchless top2.
#define BLD 264   // padded bf16 leading dim

__global__ void k1_scores(
    const float* __restrict__ X, const unsigned short* __restrict__ cbT,
    const float* __restrict__ esqs, float* __restrict__ outIdx,
    int* __restrict__ cntA, int* __restrict__ listA) {
  __shared__ __align__(16) unsigned short Bs[64 * BLD];
  __shared__ float esq_l[NCB];
  const int t = threadIdx.x;
  const int lane = t & 63, w = t >> 6;
  const int l15 = lane & 15, quad = lane >> 4;
  const int rowbase = blockIdx.x * 128;

  // stage shifted esq into LDS once
  {
    const float4 e4 = *(const float4*)(esqs + t * 4);
    *(float4*)(esq_l + t * 4) = e4;
  }

  // Preload A fragments: lane holds A[m=l15][k=quad*8+j] per (m-tile, ks).
  s16x8 afrag[2][8];
  #pragma unroll
  for (int m = 0; m < 2; ++m) {
    const float* xr = X + (size_t)(rowbase + w * 32 + m * 16 + l15) * NDIM;
    #pragma unroll
    for (int ks = 0; ks < 8; ++ks) {
      const float4 xa = *(const float4*)(xr + ks * 32 + quad * 8);
      const float4 xb = *(const float4*)(xr + ks * 32 + quad * 8 + 4);
      s16x8 a;
      a[0] = (short)f2bf(xa.x); a[1] = (short)f2bf(xa.y);
      a[2] = (short)f2bf(xa.z); a[3] = (short)f2bf(xa.w);
      a[4] = (short)f2bf(xb.x); a[5] = (short)f2bf(xb.y);
      a[6] = (short)f2bf(xb.z); a[7] = (short)f2bf(xb.w);
      afrag[m][ks] = a;
    }
  }

  int key1[2][4], key2[2][4];
  #pragma unroll
  for (int m = 0; m < 2; ++m)
    #pragma unroll
    for (int r = 0; r < 4; ++r) { key1[m][r] = 0; key2[m][r] = 0; }

  for (int nt = 0; nt < 16; ++nt) {
    const int kb = nt * 64;
    __syncthreads();
    // stage B tile: 64 cols x 256 d bf16, stored Bs[col][d] (cbT is [k][d])
    #pragma unroll
    for (int i = 0; i < 8; ++i) {
      const int id = i * 256 + t;       // [0,2048) 16B chunks
      const int c = id >> 5, d8 = id & 31;
      *(uint4*)&Bs[c * BLD + d8 * 8] = *(const uint4*)(cbT + (kb + c) * NDIM + d8 * 8);
    }
    __syncthreads();

    f32x4 acc[2][4];
    #pragma unroll
    for (int m = 0; m < 2; ++m)
      #pragma unroll
      for (int s = 0; s < 4; ++s) acc[m][s] = (f32x4){0.f, 0.f, 0.f, 0.f};

    #pragma unroll
    for (int ks = 0; ks < 8; ++ks) {
      #pragma unroll
      for (int s = 0; s < 4; ++s) {
        const s16x8 b = *(const s16x8*)&Bs[(s * 16 + l15) * BLD + ks * 32 + quad * 8];
        acc[0][s] = __builtin_amdgcn_mfma_f32_16x16x32_bf16(afrag[0][ks], b, acc[0][s], 0, 0, 0);
        acc[1][s] = __builtin_amdgcn_mfma_f32_16x16x32_bf16(afrag[1][ks], b, acc[1][s], 0, 0, 0);
      }
    }

    // epilogue: D row=(quad*4+r), col=l15 within sub-tile s. Branchless keys.
    #pragma unroll
    for (int s = 0; s < 4; ++s) {
      const int col = kb + s * 16 + l15;
      const float eq = esq_l[col];
      const int suffix = 1023 - col;
      #pragma unroll
      for (int m = 0; m < 2; ++m)
        #pragma unroll
        for (int r = 0; r < 4; ++r) {
          float sc = acc[m][s][r] - eq;          // shifted-positive score
          sc = fmaxf(sc, 1.0f);                  // safety clamp (keeps order)
          const int key = (__float_as_int(sc) & 0xFFFFFC00) | suffix;
          key2[m][r] = max(key2[m][r], min(key1[m][r], key));
          key1[m][r] = max(key1[m][r], key);
        }
    }
  }

  // merge across the 16 lanes sharing each row group (xor bits 0..3)
  #pragma unroll
  for (int mask = 1; mask <= 8; mask <<= 1) {
    #pragma unroll
    for (int m = 0; m < 2; ++m)
      #pragma unroll
      for (int r = 0; r < 4; ++r) {
        const int ok1 = __shfl_xor(key1[m][r], mask);
        const int ok2 = __shfl_xor(key2[m][r], mask);
        const int n1 = max(key1[m][r], ok1);
        const int n2 = max(min(key1[m][r], ok1), max(key2[m][r], ok2));
        key1[m][r] = n1; key2[m][r] = n2;
      }
  }

  if (l15 == 0) {
    #pragma unroll
    for (int m = 0; m < 2; ++m)
      #pragma unroll
      for (int r = 0; r < 4; ++r) {
        const int grow = rowbase + w * 32 + m * 16 + quad * 4 + r;
        outIdx[grow] = (float)(1023 - (key1[m][r] & 1023));
        const float g1 = __int_as_float(key1[m][r] & 0xFFFFFC00);
        const float g2 = __int_as_float(key2[m][r] & 0xFFFFFC00);
        if (g1 - g2 < MARGIN_A) {
          const int p = atomicAdd(cntA, 1);
          listA[p] = grow;
        }
      }
  }
}

// ---------------- k2a: fp32 recompute for contested rows ---------------------
// grid 512 x 256. Block iteration = 8 rows; thread owns 4 cols x 8 rows.
__global__ __launch_bounds__(256) void k2a_refine(
    const float* __restrict__ X, const float* __restrict__ E,
    const float* __restrict__ esq, const int* __restrict__ cntA,
    const int* __restrict__ listA, float* __restrict__ outIdx,
    int* __restrict__ cntB, int* __restrict__ listB) {
  __shared__ float Xs[8][NDIM];
  __shared__ float rv1[4][8], rv2[4][8];
  __shared__ int   ri1[4][8], ri2[4][8];
  const int t = threadIdx.x;
  const int lane = t & 63, w = t >> 6;
  const int cnt = *cntA;
  for (int base = blockIdx.x * 8; base < cnt; base += gridDim.x * 8) {
    const int nrows = min(8, cnt - base);
    __syncthreads();
    for (int r = 0; r < 8; ++r) {
      const int rid = listA[base + min(r, nrows - 1)];
      Xs[r][t] = X[(size_t)rid * NDIM + t];
    }
    __syncthreads();

    float acc[8][4];
    #pragma unroll
    for (int r = 0; r < 8; ++r)
      #pragma unroll
      for (int c = 0; c < 4; ++c) acc[r][c] = 0.f;

    const int k0 = t * 4;
    for (int d = 0; d < NDIM; ++d) {
      const float4 e = *(const float4*)(E + d * NCB + k0);
      #pragma unroll
      for (int r = 0; r < 8; ++r) {
        const float x = Xs[r][d];
        acc[r][0] += x * e.x; acc[r][1] += x * e.y;
        acc[r][2] += x * e.z; acc[r][3] += x * e.w;
      }
    }
    const float eq0 = esq[k0], eq1 = esq[k0 + 1], eq2 = esq[k0 + 2], eq3 = esq[k0 + 3];

    #pragma unroll
    for (int r = 0; r < 8; ++r) {
      float bv1 = -3.4e38f, bv2 = -3.4e38f; int bi1 = 0x7fffffff, bi2 = 0x7fffffff;
      top2_update(bv1, bi1, bv2, bi2, acc[r][0] - eq0, k0);
      top2_update(bv1, bi1, bv2, bi2, acc[r][1] - eq1, k0 + 1);
      top2_update(bv1, bi1, bv2, bi2, acc[r][2] - eq2, k0 + 2);
      top2_update(bv1, bi1, bv2, bi2, acc[r][3] - eq3, k0 + 3);
      #pragma unroll
      for (int mask = 1; mask < 64; mask <<= 1) {
        const float ov1 = __shfl_xor(bv1, mask); const int oi1 = __shfl_xor(bi1, mask);
        const float ov2 = __shfl_xor(bv2, mask); const int oi2 = __shfl_xor(bi2, mask);
        top2_merge(bv1, bi1, bv2, bi2, ov1, oi1, ov2, oi2);
      }
      if (lane == 0) { rv1[w][r] = bv1; ri1[w][r] = bi1; rv2[w][r] = bv2; ri2[w][r] = bi2; }
    }
    __syncthreads();
    if (t < nrows) {
      const int r = t;
      float fv1 = rv1[0][r], fv2 = rv2[0][r]; int fi1 = ri1[0][r], fi2 = ri2[0][r];
      for (int ww = 1; ww < 4; ++ww)
        top2_merge(fv1, fi1, fv2, fi2, rv1[ww][r], ri1[ww][r], rv2[ww][r], ri2[ww][r]);
      const int rid = listA[base + r];
      outIdx[rid] = (float)fi1;
      if (fv1 - fv2 < MARGIN_B) { const int p = atomicAdd(cntB, 1); listB[p] = rid; }
    }
    __syncthreads();
  }
}

// ---------------- k2b: reference-mimicking fp32 for near-tied rows -----------
__global__ __launch_bounds__(256) void k2b_mimic(
    const float* __restrict__ X, const float* __restrict__ E,
    const float* __restrict__ esqr, const int* __restrict__ cntB,
    const int* __restrict__ listB, float* __restrict__ outIdx) {
  __shared__ float Xr[NDIM];
  __shared__ float Psq[NDIM];
  __shared__ float rv[256];
  __shared__ int ri[256];
  const int t = threadIdx.x;
  const int cnt = *cntB;
  for (int j = blockIdx.x; j < cnt; j += gridDim.x) {
    const int rid = listB[j];
    __syncthreads();
    {
      const float x = X[(size_t)rid * NDIM + t];
      Xr[t] = x;
      Psq[t] = x * x;
    }
    __syncthreads();
    const float x_sq = np_pairwise128(Psq) + np_pairwise128(Psq + 128);

    float best = 3.4e38f; int bidx = 0x7fffffff;
    #pragma unroll
    for (int c = 0; c < 4; ++c) {
      const int k = t + c * 256;
      float acc = 0.f;
      for (int d = 0; d < NDIM; ++d)
        acc = fmaf(Xr[d], E[d * NCB + k], acc);   // strict d-order, single chain
      const float dist = (x_sq - 2.0f * acc) + esqr[k];
      if (dist < best || (dist == best && k < bidx)) { best = dist; bidx = k; }
    }
    rv[t] = best; ri[t] = bidx;
    __syncthreads();
    for (int off = 128; off > 0; off >>= 1) {
      if (t < off) {
        if (rv[t + off] < rv[t] || (rv[t + off] == rv[t] && ri[t + off] < ri[t])) {
          rv[t] = rv[t + off]; ri[t] = ri[t + off];
        }
      }
      __syncthreads();
    }
    if (t == 0) outIdx[rid] = (float)ri[0];
  }
}

// ---------------- k4: gather codeword, write quantize, diff partials ---------
__global__ __launch_bounds__(256) void k4_outputs(
    const float* __restrict__ X, const float* __restrict__ embT,
    const float* __restrict__ idxF, float* __restrict__ outQ,
    float* __restrict__ partial) {
  const int t = threadIdx.x;
  const int lane = t & 63, w = t >> 6;
  const int W = blockIdx.x * 4 + w;
  float s = 0.f;
  #pragma unroll
  for (int i = 0; i < 8; ++i) {
    const int r = W + i * 8192;
    const int idx = (int)idxF[r];
    const float4 q = *(const float4*)(embT + idx * NDIM + lane * 4);
    const float4 x = *(const float4*)(X + (size_t)r * NDIM + lane * 4);
    *(float4*)(outQ + (size_t)r * NDIM + lane * 4) = q;
    const float dx = q.x - x.x, dy = q.y - x.y, dz = q.z - x.z, dw = q.w - x.w;
    s += dx * dx + dy * dy + dz * dz + dw * dw;
  }
  #pragma unroll
  for (int mask = 1; mask < 64; mask <<= 1) s += __shfl_xor(s, mask);
  __shared__ float bs[4];
  if (lane == 0) bs[w] = s;
  __syncthreads();
  if (t == 0) partial[blockIdx.x] = (bs[0] + bs[1] + bs[2] + bs[3]) * (1.0f / 16777216.0f);
}

// ---------------- k5: final diff reduction -----------------------------------
__global__ void k5_reduce(const float* __restrict__ partial, float* __restrict__ outDiff) {
  __shared__ float s[256];
  const int t = threadIdx.x;
  float a = 0.f;
  #pragma unroll
  for (int i = 0; i < 8; ++i) a += partial[t + i * 256];
  s[t] = a;
  __syncthreads();
  for (int off = 128; off > 0; off >>= 1) {
    if (t < off) s[t] += s[t + off];
    __syncthreads();
  }
  if (t == 0) *outDiff = s[0];
}

// ---------------- launch -----------------------------------------------------
extern "C" void kernel_launch(void* const* d_in, const int* in_sizes, int n_in,
                              void* d_out, int out_size, void* d_ws, size_t ws_size,
                              hipStream_t stream) {
  const float* X = (const float*)d_in[0];     // [65536, 256]
  const float* E = (const float*)d_in[1];     // [256, 1024]
  float* out = (float*)d_out;

  char* ws = (char*)d_ws;
  unsigned short* cbT = (unsigned short*)(ws + 0x000000);  // bf16 [1024][256] 512KB
  float*  embT  = (float*) (ws + 0x080000);   // fp32 [1024][256] 1MB
  float*  esq32 = (float*) (ws + 0x180000);   // 4KB (hi-prec half-norm)
  float*  esqs  = (float*) (ws + 0x181000);   // 4KB (shifted, for k1 keys)
  float*  esqr  = (float*) (ws + 0x182000);   // 4KB (ref-mimic e_sq)
  int* cntA  = (int*)(ws + 0x183000);
  int* cntB  = (int*)(ws + 0x183004);
  int* listA = (int*)(ws + 0x183100);         // 256KB
  int* listB = (int*)(ws + 0x1C3100);         // 256KB
  float* partial = (float*)(ws + 0x203100);   // 8KB

  float* outQ    = out;
  float* outDiff = out + DIFF_OFF;
  float* outIdx  = out + IDX_OFF;

  k0a_transpose<<<dim3(64), dim3(256), 0, stream>>>(E, embT, cbT, cntA, cntB);
  k0b_esq<<<dim3(132), dim3(256), 0, stream>>>(embT, esq32, esqs, esqr);
  k1_scores<<<dim3(512), dim3(256), 0, stream>>>(X, cbT, esqs, outIdx, cntA, listA);
  k2a_refine<<<dim3(512), dim3(256), 0, stream>>>(X, E, esq32, cntA, listA, outIdx, cntB, listB);
  k2b_mimic<<<dim3(64), dim3(256), 0, stream>>>(X, E, esqr, cntB, listB, outIdx);
  k4_outputs<<<dim3(2048), dim3(256), 0, stream>>>(X, embT, outIdx, outQ, partial);
  k5_reduce<<<dim3(1), dim3(256), 0, stream>>>(partial, outDiff);
}

// Round 4
// 385.043 us; speedup vs baseline: 1.4492x; 1.0438x over previous
//
#include <hip/hip_runtime.h>

// Problem: B=65536 rows, DIM=256, K=1024 codewords.
// out layout (fp32): [0,16777216) quantize | [16777216] diff | [16777217,+65536) indices
#define NROWSQ   65536
#define NDIM     256
#define NCB      1024
#define DIFF_OFF 16777216
#define IDX_OFF  16777217

// bf16 phase-1 margin on 10-bit-quantized shifted scores (bf16 noise sigma ~0.045,
// quantization <=0.031): 0.35 ~ 7sigma.
#define MARGIN_A 0.35f
// fp32 phase-2 margin (fp32 noise ~3e-5) -> below this, numpy-mimic decides.
#define MARGIN_B 1.5e-3f
// positivity shift: score+384 in [~105, ~406] for this data; clamped >=1 for safety.
#define SCORE_SHIFT 384.0f

typedef __attribute__((ext_vector_type(8))) short s16x8;
typedef __attribute__((ext_vector_type(4))) float f32x4;

__device__ __forceinline__ unsigned short f2bf(float f) {
  union { float f; unsigned u; } v; v.f = f;
  return (unsigned short)((v.u + 0x7FFFu + ((v.u >> 16) & 1u)) >> 16);  // RNE
}

// float top2 helpers (k2a only)
__device__ __forceinline__ void top2_update(float& v1, int& i1, float& v2, int& i2,
                                            float v, int col) {
  if (v > v1 || (v == v1 && col < i1)) { v2 = v1; i2 = i1; v1 = v; i1 = col; }
  else if (v > v2 || (v == v2 && col < i2)) { v2 = v; i2 = col; }
}
__device__ __forceinline__ void top2_merge(float& v1, int& i1, float& v2, int& i2,
                                           float ov1, int oi1, float ov2, int oi2) {
  if (ov1 > v1 || (ov1 == v1 && oi1 < i1)) {
    float nv2 = v1; int ni2 = i1;
    if (ov2 > nv2 || (ov2 == nv2 && oi2 < ni2)) { nv2 = ov2; ni2 = oi2; }
    v1 = ov1; i1 = oi1; v2 = nv2; i2 = ni2;
  } else if (ov1 > v2 || (ov1 == v2 && oi1 < i2)) {
    v2 = ov1; i2 = oi1;
  }
}

// numpy pairwise_sum emulation for a contiguous 128-block (8 accumulators).
__device__ __forceinline__ float np_pairwise128(const float* p) {
  float r0 = p[0], r1 = p[1], r2 = p[2], r3 = p[3];
  float r4 = p[4], r5 = p[5], r6 = p[6], r7 = p[7];
  for (int i = 8; i < 128; i += 8) {
    r0 += p[i];     r1 += p[i + 1]; r2 += p[i + 2]; r3 += p[i + 3];
    r4 += p[i + 4]; r5 += p[i + 5]; r6 += p[i + 6]; r7 += p[i + 7];
  }
  return ((r0 + r1) + (r2 + r3)) + ((r4 + r5) + (r6 + r7));
}

// ---------------- k0a: coalesced tiled transpose E[256][1024] -> embT/cbT ----
// grid 64 x 256. block (bk=bid%16, bd=bid/16): 64x64 tile.
__global__ void k0a_transpose(const float* __restrict__ E, float* __restrict__ embT,
                              unsigned short* __restrict__ cbT,
                              int* __restrict__ cntA, int* __restrict__ cntB) {
  __shared__ float T[64][65];
  const int t = threadIdx.x;
  const int kbase = (blockIdx.x & 15) * 64;
  const int dbase = (blockIdx.x >> 4) * 64;
  if (blockIdx.x == 0 && t == 0) { *cntA = 0; *cntB = 0; }
  #pragma unroll
  for (int i = 0; i < 4; ++i) {
    const int cid = i * 256 + t;            // [0,1024) float4 chunks
    const int dl = cid >> 4, kc = cid & 15;
    const float4 v = *(const float4*)(E + (size_t)(dbase + dl) * NCB + kbase + kc * 4);
    T[dl][kc * 4 + 0] = v.x; T[dl][kc * 4 + 1] = v.y;
    T[dl][kc * 4 + 2] = v.z; T[dl][kc * 4 + 3] = v.w;
  }
  __syncthreads();
  #pragma unroll
  for (int i = 0; i < 4; ++i) {
    const int cid = i * 256 + t;
    const int kl = cid >> 4, dc = cid & 15;
    float4 v;
    v.x = T[dc * 4 + 0][kl]; v.y = T[dc * 4 + 1][kl];
    v.z = T[dc * 4 + 2][kl]; v.w = T[dc * 4 + 3][kl];
    *(float4*)(embT + (size_t)(kbase + kl) * NDIM + dbase + dc * 4) = v;
    ushort4 b;
    b.x = f2bf(v.x); b.y = f2bf(v.y); b.z = f2bf(v.z); b.w = f2bf(v.w);
    *(ushort4*)(cbT + (size_t)(kbase + kl) * NDIM + dbase + dc * 4) = b;
  }
}

// ---------------- k0b: esq variants from embT (coalesced rows) ---------------
// grid 132 x 256. blocks 0..127: esq32 (double) + shifted esqs. 128..131: esqr.
__global__ void k0b_esq(const float* __restrict__ embT, float* __restrict__ esq32,
                        float* __restrict__ esqs, float* __restrict__ esqr) {
  const int b = blockIdx.x, t = threadIdx.x;
  if (b < 128) {
    const int col = b * 8 + (t >> 5);
    const int l = t & 31;
    double s = 0.0;
    #pragma unroll
    for (int i = 0; i < 8; ++i) {
      const double v = (double)embT[(size_t)col * NDIM + l + i * 32];
      s += v * v;
    }
    #pragma unroll
    for (int m = 16; m >= 1; m >>= 1) s += __shfl_xor(s, m);
    if (l == 0) {
      esq32[col] = (float)(0.5 * s);
      esqs[col] = (float)(0.5 * s) - SCORE_SHIFT;   // score = dot - esqs (positive)
    }
  } else {
    const int col = (b - 128) * 256 + t;
    float sr = 0.f;
    for (int d = 0; d < NDIM; ++d) {
      const float v = embT[(size_t)col * NDIM + d];
      sr = sr + v * v;        // numpy axis-0 reduce: sequential fp32
    }
    esqr[col] = sr;
  }
}

// ---------------- k1: bf16 MFMA scores + packed-key top-2 + contested list ---
// grid 512 x 256 (4 waves). Block = 128 rows; wave = 32 rows (2 m-tiles of 16).
// A fragments in registers (reused across all 16 N-tiles). B tile in LDS.
// Packed key: (orderable_score_bits & ~1023) | (1023-col)  -> branchless top2.
#define BLD 264   // padded bf16 leading dim

__global__ void k1_scores(
    const float* __restrict__ X, const unsigned short* __restrict__ cbT,
    const float* __restrict__ esqs, float* __restrict__ outIdx,
    int* __restrict__ cntA, int* __restrict__ listA) {
  __shared__ __align__(16) unsigned short Bs[64 * BLD];
  __shared__ float esq_l[NCB];
  const int t = threadIdx.x;
  const int lane = t & 63, w = t >> 6;
  const int l15 = lane & 15, quad = lane >> 4;
  const int rowbase = blockIdx.x * 128;

  {
    const float4 e4 = *(const float4*)(esqs + t * 4);
    *(float4*)(esq_l + t * 4) = e4;
  }

  s16x8 afrag[2][8];
  #pragma unroll
  for (int m = 0; m < 2; ++m) {
    const float* xr = X + (size_t)(rowbase + w * 32 + m * 16 + l15) * NDIM;
    #pragma unroll
    for (int ks = 0; ks < 8; ++ks) {
      const float4 xa = *(const float4*)(xr + ks * 32 + quad * 8);
      const float4 xb = *(const float4*)(xr + ks * 32 + quad * 8 + 4);
      s16x8 a;
      a[0] = (short)f2bf(xa.x); a[1] = (short)f2bf(xa.y);
      a[2] = (short)f2bf(xa.z); a[3] = (short)f2bf(xa.w);
      a[4] = (short)f2bf(xb.x); a[5] = (short)f2bf(xb.y);
      a[6] = (short)f2bf(xb.z); a[7] = (short)f2bf(xb.w);
      afrag[m][ks] = a;
    }
  }

  int key1[2][4], key2[2][4];
  #pragma unroll
  for (int m = 0; m < 2; ++m)
    #pragma unroll
    for (int r = 0; r < 4; ++r) { key1[m][r] = 0; key2[m][r] = 0; }

  for (int nt = 0; nt < 16; ++nt) {
    const int kb = nt * 64;
    __syncthreads();
    #pragma unroll
    for (int i = 0; i < 8; ++i) {
      const int id = i * 256 + t;       // [0,2048) 16B chunks
      const int c = id >> 5, d8 = id & 31;
      *(uint4*)&Bs[c * BLD + d8 * 8] = *(const uint4*)(cbT + (kb + c) * NDIM + d8 * 8);
    }
    __syncthreads();

    f32x4 acc[2][4];
    #pragma unroll
    for (int m = 0; m < 2; ++m)
      #pragma unroll
      for (int s = 0; s < 4; ++s) acc[m][s] = (f32x4){0.f, 0.f, 0.f, 0.f};

    #pragma unroll
    for (int ks = 0; ks < 8; ++ks) {
      #pragma unroll
      for (int s = 0; s < 4; ++s) {
        const s16x8 b = *(const s16x8*)&Bs[(s * 16 + l15) * BLD + ks * 32 + quad * 8];
        acc[0][s] = __builtin_amdgcn_mfma_f32_16x16x32_bf16(afrag[0][ks], b, acc[0][s], 0, 0, 0);
        acc[1][s] = __builtin_amdgcn_mfma_f32_16x16x32_bf16(afrag[1][ks], b, acc[1][s], 0, 0, 0);
      }
    }

    #pragma unroll
    for (int s = 0; s < 4; ++s) {
      const int col = kb + s * 16 + l15;
      const float eq = esq_l[col];
      const int suffix = 1023 - col;
      #pragma unroll
      for (int m = 0; m < 2; ++m)
        #pragma unroll
        for (int r = 0; r < 4; ++r) {
          float sc = acc[m][s][r] - eq;          // shifted-positive score
          sc = fmaxf(sc, 1.0f);                  // safety clamp (keeps order)
          const int key = (__float_as_int(sc) & 0xFFFFFC00) | suffix;
          key2[m][r] = max(key2[m][r], min(key1[m][r], key));
          key1[m][r] = max(key1[m][r], key);
        }
    }
  }

  #pragma unroll
  for (int mask = 1; mask <= 8; mask <<= 1) {
    #pragma unroll
    for (int m = 0; m < 2; ++m)
      #pragma unroll
      for (int r = 0; r < 4; ++r) {
        const int ok1 = __shfl_xor(key1[m][r], mask);
        const int ok2 = __shfl_xor(key2[m][r], mask);
        const int n1 = max(key1[m][r], ok1);
        const int n2 = max(min(key1[m][r], ok1), max(key2[m][r], ok2));
        key1[m][r] = n1; key2[m][r] = n2;
      }
  }

  if (l15 == 0) {
    #pragma unroll
    for (int m = 0; m < 2; ++m)
      #pragma unroll
      for (int r = 0; r < 4; ++r) {
        const int grow = rowbase + w * 32 + m * 16 + quad * 4 + r;
        outIdx[grow] = (float)(1023 - (key1[m][r] & 1023));
        const float g1 = __int_as_float(key1[m][r] & 0xFFFFFC00);
        const float g2 = __int_as_float(key2[m][r] & 0xFFFFFC00);
        if (g1 - g2 < MARGIN_A) {
          const int p = atomicAdd(cntA, 1);
          listA[p] = grow;
        }
      }
  }
}

// ---------------- k2a: fp32 recompute for contested rows ---------------------
// grid 512 x 256. Block iteration = 16 rows (halves E re-reads vs 8); thread
// owns 4 cols x 16 rows = 64 accumulators.
#define K2A_ROWS 16
__global__ __launch_bounds__(256) void k2a_refine(
    const float* __restrict__ X, const float* __restrict__ E,
    const float* __restrict__ esq, const int* __restrict__ cntA,
    const int* __restrict__ listA, float* __restrict__ outIdx,
    int* __restrict__ cntB, int* __restrict__ listB) {
  __shared__ float Xs[K2A_ROWS][NDIM];
  __shared__ float rv1[4][K2A_ROWS], rv2[4][K2A_ROWS];
  __shared__ int   ri1[4][K2A_ROWS], ri2[4][K2A_ROWS];
  const int t = threadIdx.x;
  const int lane = t & 63, w = t >> 6;
  const int cnt = *cntA;
  for (int base = blockIdx.x * K2A_ROWS; base < cnt; base += gridDim.x * K2A_ROWS) {
    const int nrows = min(K2A_ROWS, cnt - base);
    __syncthreads();
    for (int r = 0; r < K2A_ROWS; ++r) {
      const int rid = listA[base + min(r, nrows - 1)];
      Xs[r][t] = X[(size_t)rid * NDIM + t];
    }
    __syncthreads();

    float acc[K2A_ROWS][4];
    #pragma unroll
    for (int r = 0; r < K2A_ROWS; ++r)
      #pragma unroll
      for (int c = 0; c < 4; ++c) acc[r][c] = 0.f;

    const int k0 = t * 4;
    for (int d = 0; d < NDIM; ++d) {
      const float4 e = *(const float4*)(E + d * NCB + k0);
      #pragma unroll
      for (int r = 0; r < K2A_ROWS; ++r) {
        const float x = Xs[r][d];
        acc[r][0] += x * e.x; acc[r][1] += x * e.y;
        acc[r][2] += x * e.z; acc[r][3] += x * e.w;
      }
    }
    const float eq0 = esq[k0], eq1 = esq[k0 + 1], eq2 = esq[k0 + 2], eq3 = esq[k0 + 3];

    #pragma unroll
    for (int r = 0; r < K2A_ROWS; ++r) {
      float bv1 = -3.4e38f, bv2 = -3.4e38f; int bi1 = 0x7fffffff, bi2 = 0x7fffffff;
      top2_update(bv1, bi1, bv2, bi2, acc[r][0] - eq0, k0);
      top2_update(bv1, bi1, bv2, bi2, acc[r][1] - eq1, k0 + 1);
      top2_update(bv1, bi1, bv2, bi2, acc[r][2] - eq2, k0 + 2);
      top2_update(bv1, bi1, bv2, bi2, acc[r][3] - eq3, k0 + 3);
      #pragma unroll
      for (int mask = 1; mask < 64; mask <<= 1) {
        const float ov1 = __shfl_xor(bv1, mask); const int oi1 = __shfl_xor(bi1, mask);
        const float ov2 = __shfl_xor(bv2, mask); const int oi2 = __shfl_xor(bi2, mask);
        top2_merge(bv1, bi1, bv2, bi2, ov1, oi1, ov2, oi2);
      }
      if (lane == 0) { rv1[w][r] = bv1; ri1[w][r] = bi1; rv2[w][r] = bv2; ri2[w][r] = bi2; }
    }
    __syncthreads();
    if (t < nrows) {
      const int r = t;
      float fv1 = rv1[0][r], fv2 = rv2[0][r]; int fi1 = ri1[0][r], fi2 = ri2[0][r];
      for (int ww = 1; ww < 4; ++ww)
        top2_merge(fv1, fi1, fv2, fi2, rv1[ww][r], ri1[ww][r], rv2[ww][r], ri2[ww][r]);
      const int rid = listA[base + r];
      outIdx[rid] = (float)fi1;
      if (fv1 - fv2 < MARGIN_B) { const int p = atomicAdd(cntB, 1); listB[p] = rid; }
    }
    __syncthreads();
  }
}

// ---------------- k2b: reference-mimicking fp32 for near-tied rows -----------
// Reads embT (k-major, bit-identical values to E) so the strict d-order FMA
// chain consumes contiguous float4 loads instead of 4KB-strided scalars.
__global__ __launch_bounds__(256) void k2b_mimic(
    const float* __restrict__ X, const float* __restrict__ embT,
    const float* __restrict__ esqr, const int* __restrict__ cntB,
    const int* __restrict__ listB, float* __restrict__ outIdx) {
  __shared__ float Xr[NDIM];
  __shared__ float Psq[NDIM];
  __shared__ float rv[256];
  __shared__ int ri[256];
  const int t = threadIdx.x;
  const int cnt = *cntB;
  for (int j = blockIdx.x; j < cnt; j += gridDim.x) {
    const int rid = listB[j];
    __syncthreads();
    {
      const float x = X[(size_t)rid * NDIM + t];
      Xr[t] = x;
      Psq[t] = x * x;
    }
    __syncthreads();
    const float x_sq = np_pairwise128(Psq) + np_pairwise128(Psq + 128);

    float best = 3.4e38f; int bidx = 0x7fffffff;
    #pragma unroll
    for (int c = 0; c < 4; ++c) {
      const int k = t + c * 256;
      const float* er = embT + (size_t)k * NDIM;
      float acc = 0.f;
      #pragma unroll 8
      for (int dq = 0; dq < 64; ++dq) {
        const float4 e = *(const float4*)(er + dq * 4);
        const float4 x = *(const float4*)(Xr + dq * 4);
        acc = fmaf(x.x, e.x, acc);   // strict d-order chain (OpenBLAS mimic)
        acc = fmaf(x.y, e.y, acc);
        acc = fmaf(x.z, e.z, acc);
        acc = fmaf(x.w, e.w, acc);
      }
      const float dist = (x_sq - 2.0f * acc) + esqr[k];
      if (dist < best || (dist == best && k < bidx)) { best = dist; bidx = k; }
    }
    rv[t] = best; ri[t] = bidx;
    __syncthreads();
    for (int off = 128; off > 0; off >>= 1) {
      if (t < off) {
        if (rv[t + off] < rv[t] || (rv[t + off] == rv[t] && ri[t + off] < ri[t])) {
          rv[t] = rv[t + off]; ri[t] = ri[t + off];
        }
      }
      __syncthreads();
    }
    if (t == 0) outIdx[rid] = (float)ri[0];
  }
}

// ---------------- k4: gather codeword, write quantize, diff partials ---------
__global__ __launch_bounds__(256) void k4_outputs(
    const float* __restrict__ X, const float* __restrict__ embT,
    const float* __restrict__ idxF, float* __restrict__ outQ,
    float* __restrict__ partial) {
  const int t = threadIdx.x;
  const int lane = t & 63, w = t >> 6;
  const int W = blockIdx.x * 4 + w;
  float s = 0.f;
  #pragma unroll
  for (int i = 0; i < 8; ++i) {
    const int r = W + i * 8192;
    const int idx = (int)idxF[r];
    const float4 q = *(const float4*)(embT + idx * NDIM + lane * 4);
    const float4 x = *(const float4*)(X + (size_t)r * NDIM + lane * 4);
    *(float4*)(outQ + (size_t)r * NDIM + lane * 4) = q;
    const float dx = q.x - x.x, dy = q.y - x.y, dz = q.z - x.z, dw = q.w - x.w;
    s += dx * dx + dy * dy + dz * dz + dw * dw;
  }
  #pragma unroll
  for (int mask = 1; mask < 64; mask <<= 1) s += __shfl_xor(s, mask);
  __shared__ float bs[4];
  if (lane == 0) bs[w] = s;
  __syncthreads();
  if (t == 0) partial[blockIdx.x] = (bs[0] + bs[1] + bs[2] + bs[3]) * (1.0f / 16777216.0f);
}

// ---------------- k5: final diff reduction -----------------------------------
__global__ void k5_reduce(const float* __restrict__ partial, float* __restrict__ outDiff) {
  __shared__ float s[256];
  const int t = threadIdx.x;
  float a = 0.f;
  #pragma unroll
  for (int i = 0; i < 8; ++i) a += partial[t + i * 256];
  s[t] = a;
  __syncthreads();
  for (int off = 128; off > 0; off >>= 1) {
    if (t < off) s[t] += s[t + off];
    __syncthreads();
  }
  if (t == 0) *outDiff = s[0];
}

// ---------------- launch -----------------------------------------------------
extern "C" void kernel_launch(void* const* d_in, const int* in_sizes, int n_in,
                              void* d_out, int out_size, void* d_ws, size_t ws_size,
                              hipStream_t stream) {
  const float* X = (const float*)d_in[0];     // [65536, 256]
  const float* E = (const float*)d_in[1];     // [256, 1024]
  float* out = (float*)d_out;

  char* ws = (char*)d_ws;
  unsigned short* cbT = (unsigned short*)(ws + 0x000000);  // bf16 [1024][256] 512KB
  float*  embT  = (float*) (ws + 0x080000);   // fp32 [1024][256] 1MB
  float*  esq32 = (float*) (ws + 0x180000);   // 4KB (hi-prec half-norm)
  float*  esqs  = (float*) (ws + 0x181000);   // 4KB (shifted, for k1 keys)
  float*  esqr  = (float*) (ws + 0x182000);   // 4KB (ref-mimic e_sq)
  int* cntA  = (int*)(ws + 0x183000);
  int* cntB  = (int*)(ws + 0x183004);
  int* listA = (int*)(ws + 0x183100);         // 256KB
  int* listB = (int*)(ws + 0x1C3100);         // 256KB
  float* partial = (float*)(ws + 0x203100);   // 8KB

  float* outQ    = out;
  float* outDiff = out + DIFF_OFF;
  float* outIdx  = out + IDX_OFF;

  k0a_transpose<<<dim3(64), dim3(256), 0, stream>>>(E, embT, cbT, cntA, cntB);
  k0b_esq<<<dim3(132), dim3(256), 0, stream>>>(embT, esq32, esqs, esqr);
  k1_scores<<<dim3(512), dim3(256), 0, stream>>>(X, cbT, esqs, outIdx, cntA, listA);
  k2a_refine<<<dim3(512), dim3(256), 0, stream>>>(X, E, esq32, cntA, listA, outIdx, cntB, listB);
  k2b_mimic<<<dim3(64), dim3(256), 0, stream>>>(X, embT, esqr, cntB, listB, outIdx);
  k4_outputs<<<dim3(2048), dim3(256), 0, stream>>>(X, embT, outIdx, outQ, partial);
  k5_reduce<<<dim3(1), dim3(256), 0, stream>>>(partial, outDiff);
}

// Round 5
// 344.615 us; speedup vs baseline: 1.6192x; 1.1173x over previous
//
#include <hip/hip_runtime.h>

// Problem: B=65536 rows, DIM=256, K=1024 codewords.
// out layout (fp32): [0,16777216) quantize | [16777216] diff | [16777217,+65536) indices
#define NROWSQ   65536
#define NDIM     256
#define NCB      1024
#define DIFF_OFF 16777216
#define IDX_OFF  16777217

// bf16 phase-1 margin on 10-bit-quantized shifted scores (~7 sigma)
#define MARGIN_A 0.35f
// fp32 phase-2 margin -> below this, numpy-mimic decides.
#define MARGIN_B 1.5e-3f
// positivity shift: score+384 in [~105, ~406]; clamped >=1 for safety.
#define SCORE_SHIFT 384.0f

typedef __attribute__((ext_vector_type(8))) short s16x8;
typedef __attribute__((ext_vector_type(4))) float f32x4;

__device__ __forceinline__ unsigned short f2bf(float f) {
  union { float f; unsigned u; } v; v.f = f;
  return (unsigned short)((v.u + 0x7FFFu + ((v.u >> 16) & 1u)) >> 16);  // RNE
}

__device__ __forceinline__ void top2_update(float& v1, int& i1, float& v2, int& i2,
                                            float v, int col) {
  if (v > v1 || (v == v1 && col < i1)) { v2 = v1; i2 = i1; v1 = v; i1 = col; }
  else if (v > v2 || (v == v2 && col < i2)) { v2 = v; i2 = col; }
}
__device__ __forceinline__ void top2_merge(float& v1, int& i1, float& v2, int& i2,
                                           float ov1, int oi1, float ov2, int oi2) {
  if (ov1 > v1 || (ov1 == v1 && oi1 < i1)) {
    float nv2 = v1; int ni2 = i1;
    if (ov2 > nv2 || (ov2 == nv2 && oi2 < ni2)) { nv2 = ov2; ni2 = oi2; }
    v1 = ov1; i1 = oi1; v2 = nv2; i2 = ni2;
  } else if (ov1 > v2 || (ov1 == v2 && oi1 < i2)) {
    v2 = ov1; i2 = oi1;
  }
}

// numpy pairwise_sum emulation for a contiguous 128-block (8 accumulators).
__device__ __forceinline__ float np_pairwise128(const float* p) {
  float r0 = p[0], r1 = p[1], r2 = p[2], r3 = p[3];
  float r4 = p[4], r5 = p[5], r6 = p[6], r7 = p[7];
  for (int i = 8; i < 128; i += 8) {
    r0 += p[i];     r1 += p[i + 1]; r2 += p[i + 2]; r3 += p[i + 3];
    r4 += p[i + 4]; r5 += p[i + 5]; r6 += p[i + 6]; r7 += p[i + 7];
  }
  return ((r0 + r1) + (r2 + r3)) + ((r4 + r5) + (r6 + r7));
}

// ---------------- k0a: coalesced tiled transpose E[256][1024] -> embT/cbT ----
__global__ void k0a_transpose(const float* __restrict__ E, float* __restrict__ embT,
                              unsigned short* __restrict__ cbT,
                              int* __restrict__ cntA, int* __restrict__ cntB) {
  __shared__ float T[64][65];
  const int t = threadIdx.x;
  const int kbase = (blockIdx.x & 15) * 64;
  const int dbase = (blockIdx.x >> 4) * 64;
  if (blockIdx.x == 0 && t == 0) { *cntA = 0; *cntB = 0; }
  #pragma unroll
  for (int i = 0; i < 4; ++i) {
    const int cid = i * 256 + t;
    const int dl = cid >> 4, kc = cid & 15;
    const float4 v = *(const float4*)(E + (size_t)(dbase + dl) * NCB + kbase + kc * 4);
    T[dl][kc * 4 + 0] = v.x; T[dl][kc * 4 + 1] = v.y;
    T[dl][kc * 4 + 2] = v.z; T[dl][kc * 4 + 3] = v.w;
  }
  __syncthreads();
  #pragma unroll
  for (int i = 0; i < 4; ++i) {
    const int cid = i * 256 + t;
    const int kl = cid >> 4, dc = cid & 15;
    float4 v;
    v.x = T[dc * 4 + 0][kl]; v.y = T[dc * 4 + 1][kl];
    v.z = T[dc * 4 + 2][kl]; v.w = T[dc * 4 + 3][kl];
    *(float4*)(embT + (size_t)(kbase + kl) * NDIM + dbase + dc * 4) = v;
    ushort4 b;
    b.x = f2bf(v.x); b.y = f2bf(v.y); b.z = f2bf(v.z); b.w = f2bf(v.w);
    *(ushort4*)(cbT + (size_t)(kbase + kl) * NDIM + dbase + dc * 4) = b;
  }
}

// ---------------- k0b: esq variants from embT (coalesced rows) ---------------
__global__ void k0b_esq(const float* __restrict__ embT, float* __restrict__ esq32,
                        float* __restrict__ esqs, float* __restrict__ esqr) {
  const int b = blockIdx.x, t = threadIdx.x;
  if (b < 128) {
    const int col = b * 8 + (t >> 5);
    const int l = t & 31;
    double s = 0.0;
    #pragma unroll
    for (int i = 0; i < 8; ++i) {
      const double v = (double)embT[(size_t)col * NDIM + l + i * 32];
      s += v * v;
    }
    #pragma unroll
    for (int m = 16; m >= 1; m >>= 1) s += __shfl_xor(s, m);
    if (l == 0) {
      esq32[col] = (float)(0.5 * s);
      esqs[col] = (float)(0.5 * s) - SCORE_SHIFT;
    }
  } else {
    const int col = (b - 128) * 256 + t;
    float sr = 0.f;
    for (int d = 0; d < NDIM; ++d) {
      const float v = embT[(size_t)col * NDIM + d];
      sr = sr + v * v;        // numpy axis-0 reduce: sequential fp32
    }
    esqr[col] = sr;
  }
}

// ---------------- k1: bf16 MFMA scores, column-split 2-way -------------------
// grid 1024: rowtile = bid>>1 (128 rows), half = bid&1 (512 cols, 8 N-tiles).
// 4 blocks/CU (LDS ~36KB) -> 16 waves/CU. Writes packed top-2 keys per row.
#define BLD 264   // padded bf16 leading dim

__global__ void k1_scores(
    const float* __restrict__ X, const unsigned short* __restrict__ cbT,
    const float* __restrict__ esqs, int2* __restrict__ part1) {
  __shared__ __align__(16) unsigned short Bs[64 * BLD];
  __shared__ float esq_l[512];
  const int t = threadIdx.x;
  const int lane = t & 63, w = t >> 6;
  const int l15 = lane & 15, quad = lane >> 4;
  const int half = blockIdx.x & 1;
  const int rowbase = (blockIdx.x >> 1) * 128;
  const int colbase = half * 512;

  {
    const float2 e2 = *(const float2*)(esqs + colbase + t * 2);
    *(float2*)(esq_l + t * 2) = e2;
  }

  // A fragments: lane holds A[m=l15][k=quad*8+j] per (m-tile, ks).
  s16x8 afrag[2][8];
  #pragma unroll
  for (int m = 0; m < 2; ++m) {
    const float* xr = X + (size_t)(rowbase + w * 32 + m * 16 + l15) * NDIM;
    #pragma unroll
    for (int ks = 0; ks < 8; ++ks) {
      const float4 xa = *(const float4*)(xr + ks * 32 + quad * 8);
      const float4 xb = *(const float4*)(xr + ks * 32 + quad * 8 + 4);
      s16x8 a;
      a[0] = (short)f2bf(xa.x); a[1] = (short)f2bf(xa.y);
      a[2] = (short)f2bf(xa.z); a[3] = (short)f2bf(xa.w);
      a[4] = (short)f2bf(xb.x); a[5] = (short)f2bf(xb.y);
      a[6] = (short)f2bf(xb.z); a[7] = (short)f2bf(xb.w);
      afrag[m][ks] = a;
    }
  }

  int key1[2][4], key2[2][4];
  #pragma unroll
  for (int m = 0; m < 2; ++m)
    #pragma unroll
    for (int r = 0; r < 4; ++r) { key1[m][r] = 0; key2[m][r] = 0; }

  for (int nt = 0; nt < 8; ++nt) {
    __syncthreads();
    // stage B tile: 64 cols x 256 d bf16 -> Bs[col][d]
    #pragma unroll
    for (int i = 0; i < 8; ++i) {
      const int id = i * 256 + t;       // [0,2048) 16B chunks
      const int c = id >> 5, d8 = id & 31;
      *(uint4*)&Bs[c * BLD + d8 * 8] =
          *(const uint4*)(cbT + (size_t)(colbase + nt * 64 + c) * NDIM + d8 * 8);
    }
    __syncthreads();

    f32x4 acc[2][4];
    #pragma unroll
    for (int m = 0; m < 2; ++m)
      #pragma unroll
      for (int s = 0; s < 4; ++s) acc[m][s] = (f32x4){0.f, 0.f, 0.f, 0.f};

    #pragma unroll
    for (int ks = 0; ks < 8; ++ks) {
      #pragma unroll
      for (int s = 0; s < 4; ++s) {
        const s16x8 b = *(const s16x8*)&Bs[(s * 16 + l15) * BLD + ks * 32 + quad * 8];
        acc[0][s] = __builtin_amdgcn_mfma_f32_16x16x32_bf16(afrag[0][ks], b, acc[0][s], 0, 0, 0);
        acc[1][s] = __builtin_amdgcn_mfma_f32_16x16x32_bf16(afrag[1][ks], b, acc[1][s], 0, 0, 0);
      }
    }

    #pragma unroll
    for (int s = 0; s < 4; ++s) {
      const int lcol = nt * 64 + s * 16 + l15;
      const float eq = esq_l[lcol];
      const int suffix = 1023 - (colbase + lcol);
      #pragma unroll
      for (int m = 0; m < 2; ++m)
        #pragma unroll
        for (int r = 0; r < 4; ++r) {
          float sc = acc[m][s][r] - eq;
          sc = fmaxf(sc, 1.0f);
          const int key = (__float_as_int(sc) & 0xFFFFFC00) | suffix;
          key2[m][r] = max(key2[m][r], min(key1[m][r], key));
          key1[m][r] = max(key1[m][r], key);
        }
    }
  }

  #pragma unroll
  for (int mask = 1; mask <= 8; mask <<= 1) {
    #pragma unroll
    for (int m = 0; m < 2; ++m)
      #pragma unroll
      for (int r = 0; r < 4; ++r) {
        const int ok1 = __shfl_xor(key1[m][r], mask);
        const int ok2 = __shfl_xor(key2[m][r], mask);
        const int n1 = max(key1[m][r], ok1);
        const int n2 = max(min(key1[m][r], ok1), max(key2[m][r], ok2));
        key1[m][r] = n1; key2[m][r] = n2;
      }
  }

  if (l15 == 0) {
    #pragma unroll
    for (int m = 0; m < 2; ++m)
      #pragma unroll
      for (int r = 0; r < 4; ++r) {
        const int grow = rowbase + w * 32 + m * 16 + quad * 4 + r;
        part1[half * NROWSQ + grow] = make_int2(key1[m][r], key2[m][r]);
      }
  }
}

// ---------------- k1m: merge halves, write idx, build listA, zero diff -------
__global__ void k1m_merge(const int2* __restrict__ part1, float* __restrict__ outIdx,
                          int* __restrict__ cntA, int* __restrict__ listA,
                          float* __restrict__ outDiff) {
  const int row = blockIdx.x * 256 + threadIdx.x;
  if (row == 0) *outDiff = 0.f;
  const int2 a = part1[row];
  const int2 b = part1[NROWSQ + row];
  const int k1 = max(a.x, b.x);
  const int k2 = max(min(a.x, b.x), max(a.y, b.y));
  outIdx[row] = (float)(1023 - (k1 & 1023));
  const float g1 = __int_as_float(k1 & 0xFFFFFC00);
  const float g2 = __int_as_float(k2 & 0xFFFFFC00);
  if (g1 - g2 < MARGIN_A) {
    const int p = atomicAdd(cntA, 1);
    listA[p] = row;
  }
}

// ---------------- k2a: fp32 recompute for contested rows, column-split -------
// grid 1024: half = bid&1 (512 cols), row-chunks of 8 strided across bid>>1.
__global__ __launch_bounds__(256) void k2a_refine(
    const float* __restrict__ X, const float* __restrict__ E,
    const float* __restrict__ esq, const int* __restrict__ cntA,
    const int* __restrict__ listA, float4* __restrict__ part2) {
  __shared__ float Xs[8][NDIM];
  __shared__ float rv1[4][8], rv2[4][8];
  __shared__ int   ri1[4][8], ri2[4][8];
  const int t = threadIdx.x;
  const int lane = t & 63, w = t >> 6;
  const int half = blockIdx.x & 1;
  const int bstride = gridDim.x >> 1;
  const int cnt = *cntA;
  const int k0 = half * 512 + t * 2;
  for (int base = (blockIdx.x >> 1) * 8; base < cnt; base += bstride * 8) {
    const int nrows = min(8, cnt - base);
    __syncthreads();
    for (int r = 0; r < 8; ++r) {
      const int rid = listA[base + min(r, nrows - 1)];
      Xs[r][t] = X[(size_t)rid * NDIM + t];
    }
    __syncthreads();

    float acc[8][2];
    #pragma unroll
    for (int r = 0; r < 8; ++r) { acc[r][0] = 0.f; acc[r][1] = 0.f; }

    for (int d = 0; d < NDIM; ++d) {
      const float2 e = *(const float2*)(E + d * NCB + k0);
      #pragma unroll
      for (int r = 0; r < 8; ++r) {
        const float x = Xs[r][d];
        acc[r][0] += x * e.x; acc[r][1] += x * e.y;
      }
    }
    const float eq0 = esq[k0], eq1 = esq[k0 + 1];

    #pragma unroll
    for (int r = 0; r < 8; ++r) {
      float bv1 = -3.4e38f, bv2 = -3.4e38f; int bi1 = 0x7fffffff, bi2 = 0x7fffffff;
      top2_update(bv1, bi1, bv2, bi2, acc[r][0] - eq0, k0);
      top2_update(bv1, bi1, bv2, bi2, acc[r][1] - eq1, k0 + 1);
      #pragma unroll
      for (int mask = 1; mask < 64; mask <<= 1) {
        const float ov1 = __shfl_xor(bv1, mask); const int oi1 = __shfl_xor(bi1, mask);
        const float ov2 = __shfl_xor(bv2, mask); const int oi2 = __shfl_xor(bi2, mask);
        top2_merge(bv1, bi1, bv2, bi2, ov1, oi1, ov2, oi2);
      }
      if (lane == 0) { rv1[w][r] = bv1; ri1[w][r] = bi1; rv2[w][r] = bv2; ri2[w][r] = bi2; }
    }
    __syncthreads();
    if (t < nrows) {
      const int r = t;
      float fv1 = rv1[0][r], fv2 = rv2[0][r]; int fi1 = ri1[0][r], fi2 = ri2[0][r];
      for (int ww = 1; ww < 4; ++ww)
        top2_merge(fv1, fi1, fv2, fi2, rv1[ww][r], ri1[ww][r], rv2[ww][r], ri2[ww][r]);
      part2[half * NROWSQ + base + r] = make_float4(fv1, (float)fi1, fv2, (float)fi2);
    }
    __syncthreads();
  }
}

// ---------------- k2m: merge k2a halves, write idx, build listB --------------
__global__ void k2m_merge(const float4* __restrict__ part2, const int* __restrict__ cntA,
                          const int* __restrict__ listA, float* __restrict__ outIdx,
                          int* __restrict__ cntB, int* __restrict__ listB) {
  const int cnt = *cntA;
  for (int j = blockIdx.x * 256 + threadIdx.x; j < cnt; j += gridDim.x * 256) {
    const float4 a = part2[j];
    const float4 b = part2[NROWSQ + j];
    float v1 = a.x, v2 = a.z; int i1 = (int)a.y, i2 = (int)a.w;
    top2_merge(v1, i1, v2, i2, b.x, (int)b.y, b.z, (int)b.w);
    const int rid = listA[j];
    outIdx[rid] = (float)i1;
    if (v1 - v2 < MARGIN_B) { const int p = atomicAdd(cntB, 1); listB[p] = rid; }
  }
}

// ---------------- k2b: reference-mimicking fp32 for near-tied rows -----------
__global__ __launch_bounds__(256) void k2b_mimic(
    const float* __restrict__ X, const float* __restrict__ embT,
    const float* __restrict__ esqr, const int* __restrict__ cntB,
    const int* __restrict__ listB, float* __restrict__ outIdx) {
  __shared__ float Xr[NDIM];
  __shared__ float Psq[NDIM];
  __shared__ float rv[256];
  __shared__ int ri[256];
  const int t = threadIdx.x;
  const int cnt = *cntB;
  for (int j = blockIdx.x; j < cnt; j += gridDim.x) {
    const int rid = listB[j];
    __syncthreads();
    {
      const float x = X[(size_t)rid * NDIM + t];
      Xr[t] = x;
      Psq[t] = x * x;
    }
    __syncthreads();
    const float x_sq = np_pairwise128(Psq) + np_pairwise128(Psq + 128);

    float best = 3.4e38f; int bidx = 0x7fffffff;
    #pragma unroll
    for (int c = 0; c < 4; ++c) {
      const int k = t + c * 256;
      const float* er = embT + (size_t)k * NDIM;
      float acc = 0.f;
      #pragma unroll 8
      for (int dq = 0; dq < 64; ++dq) {
        const float4 e = *(const float4*)(er + dq * 4);
        const float4 x = *(const float4*)(Xr + dq * 4);
        acc = fmaf(x.x, e.x, acc);   // strict d-order chain (OpenBLAS mimic)
        acc = fmaf(x.y, e.y, acc);
        acc = fmaf(x.z, e.z, acc);
        acc = fmaf(x.w, e.w, acc);
      }
      const float dist = (x_sq - 2.0f * acc) + esqr[k];
      if (dist < best || (dist == best && k < bidx)) { best = dist; bidx = k; }
    }
    rv[t] = best; ri[t] = bidx;
    __syncthreads();
    for (int off = 128; off > 0; off >>= 1) {
      if (t < off) {
        if (rv[t + off] < rv[t] || (rv[t + off] == rv[t] && ri[t + off] < ri[t])) {
          rv[t] = rv[t + off]; ri[t] = ri[t + off];
        }
      }
      __syncthreads();
    }
    if (t == 0) outIdx[rid] = (float)ri[0];
  }
}

// ---------------- k4: gather codeword, write quantize, diff atomic -----------
__global__ __launch_bounds__(256) void k4_outputs(
    const float* __restrict__ X, const float* __restrict__ embT,
    const float* __restrict__ idxF, float* __restrict__ outQ,
    float* __restrict__ outDiff) {
  const int t = threadIdx.x;
  const int lane = t & 63, w = t >> 6;
  const int W = blockIdx.x * 4 + w;
  float s = 0.f;
  #pragma unroll
  for (int i = 0; i < 8; ++i) {
    const int r = W + i * 8192;
    const int idx = (int)idxF[r];
    const float4 q = *(const float4*)(embT + idx * NDIM + lane * 4);
    const float4 x = *(const float4*)(X + (size_t)r * NDIM + lane * 4);
    *(float4*)(outQ + (size_t)r * NDIM + lane * 4) = q;
    const float dx = q.x - x.x, dy = q.y - x.y, dz = q.z - x.z, dw = q.w - x.w;
    s += dx * dx + dy * dy + dz * dz + dw * dw;
  }
  #pragma unroll
  for (int mask = 1; mask < 64; mask <<= 1) s += __shfl_xor(s, mask);
  __shared__ float bs[4];
  if (lane == 0) bs[w] = s;
  __syncthreads();
  if (t == 0)
    atomicAdd(outDiff, (bs[0] + bs[1] + bs[2] + bs[3]) * (1.0f / 16777216.0f));
}

// ---------------- launch -----------------------------------------------------
extern "C" void kernel_launch(void* const* d_in, const int* in_sizes, int n_in,
                              void* d_out, int out_size, void* d_ws, size_t ws_size,
                              hipStream_t stream) {
  const float* X = (const float*)d_in[0];     // [65536, 256]
  const float* E = (const float*)d_in[1];     // [256, 1024]
  float* out = (float*)d_out;

  char* ws = (char*)d_ws;                     // ~5.1 MB used
  unsigned short* cbT = (unsigned short*)(ws + 0x000000);  // bf16 [1024][256] 512KB
  float*  embT  = (float*) (ws + 0x080000);   // fp32 [1024][256] 1MB
  float*  esq32 = (float*) (ws + 0x180000);   // 4KB (hi-prec half-norm)
  float*  esqs  = (float*) (ws + 0x181000);   // 4KB (shifted, for k1 keys)
  float*  esqr  = (float*) (ws + 0x182000);   // 4KB (ref-mimic e_sq)
  int* cntA  = (int*)(ws + 0x183000);
  int* cntB  = (int*)(ws + 0x183004);
  int* listA = (int*)(ws + 0x183100);         // 256KB
  int* listB = (int*)(ws + 0x1C3100);         // 256KB
  int2*   part1 = (int2*)  (ws + 0x203100);   // 2 x 65536 x 8B = 1MB
  float4* part2 = (float4*)(ws + 0x303100);   // 2 x 65536 x 16B = 2MB

  float* outQ    = out;
  float* outDiff = out + DIFF_OFF;
  float* outIdx  = out + IDX_OFF;

  k0a_transpose<<<dim3(64), dim3(256), 0, stream>>>(E, embT, cbT, cntA, cntB);
  k0b_esq<<<dim3(132), dim3(256), 0, stream>>>(embT, esq32, esqs, esqr);
  k1_scores<<<dim3(1024), dim3(256), 0, stream>>>(X, cbT, esqs, part1);
  k1m_merge<<<dim3(256), dim3(256), 0, stream>>>(part1, outIdx, cntA, listA, outDiff);
  k2a_refine<<<dim3(1024), dim3(256), 0, stream>>>(X, E, esq32, cntA, listA, part2);
  k2m_merge<<<dim3(64), dim3(256), 0, stream>>>(part2, cntA, listA, outIdx, cntB, listB);
  k2b_mimic<<<dim3(64), dim3(256), 0, stream>>>(X, embT, esqr, cntB, listB, outIdx);
  k4_outputs<<<dim3(2048), dim3(256), 0, stream>>>(X, embT, outIdx, outQ, outDiff);
}